// Round 1
// baseline (294.482 us; speedup 1.0000x reference)
//
#include <hip/hip_runtime.h>
#include <hip/hip_bf16.h>

#define NN 1048576
#define NG 16384
#define DD 128

typedef __bf16 bf16x8 __attribute__((ext_vector_type(8)));
typedef float f32x4 __attribute__((ext_vector_type(4)));
typedef unsigned short us8v __attribute__((ext_vector_type(8)));

__device__ __forceinline__ unsigned short f2bf(float f) {
    unsigned int u = __float_as_uint(f);
    u += 0x7FFFu + ((u >> 16) & 1u);
    return (unsigned short)(u >> 16);
}

__global__ void prep_kernel(const int* __restrict__ gid, const float* __restrict__ W,
                            int* __restrict__ starts, unsigned short* __restrict__ Wt) {
    int t = blockIdx.x * 256 + threadIdx.x;
    if (t <= NG) {
        int lo = 0, hi = NN;
        while (lo < hi) { int mid = (lo + hi) >> 1; if (gid[mid] < t) lo = mid + 1; else hi = mid; }
        starts[t] = lo;
    }
    if (t < DD * DD) {
        int k = t >> 7, n = t & 127;           // W is [k][n]
        Wt[n * DD + k] = f2bf(W[t]);           // Wt is [n][k]
    }
}

__global__ __launch_bounds__(256, 2) void fused_kernel(
    const float* __restrict__ x, const int* __restrict__ starts,
    const unsigned short* __restrict__ Wt,
    const float* __restrict__ b_enc, const float* __restrict__ w_q1,
    const float* __restrict__ b_q1, const float* __restrict__ w_q2,
    const float* __restrict__ b_q2, float* __restrict__ out) {

    __shared__ unsigned short Wt_lds[DD][136];   // [col][k], padded pitch
    __shared__ float h_lds[64][132];             // fp32 h chunk, padded
    __shared__ float s1_lds[64], s2_lds[64], e1_lds[64], e2_lds[64];
    __shared__ float b_lds[DD], w1_lds[DD], w2_lds[DD];
    __shared__ float tmp_lds[3][DD];

    const int t = threadIdx.x;
    const int w = t >> 6, l = t & 63;
    const int lr = l & 15, lk = l >> 4;

    // ---- stage W (bf16, [col][k]) + small vectors into LDS ----
    for (int i = t; i < (DD * DD) / 8; i += 256) {
        const int f = i * 8;
        us8v v = *(const us8v*)(Wt + f);
        *(us8v*)&Wt_lds[f >> 7][f & 127] = v;
    }
    if (t < DD) { b_lds[t] = b_enc[t]; w1_lds[t] = w_q1[t]; w2_lds[t] = w_q2[t]; }
    const float bq1 = b_q1[0], bq2 = b_q2[0];
    __syncthreads();

    for (int g = blockIdx.x; g < NG; g += gridDim.x) {
        const int seg0 = starts[g], seg1 = starts[g + 1];
        const int cnt = seg1 - seg0;
        const int c = t & 127, hf = t >> 7;
        float m1 = -INFINITY, m2 = -INFINITY, z1 = 0.f, z2 = 0.f;
        float ka = 0.f, q1a = 0.f, q2a = 0.f;

        for (int c0 = seg0; c0 < seg1; c0 += 64) {
            __syncthreads();   // protect h/s/e LDS reuse across chunks/graphs

            // ---- phase A: h = relu(x W + b) via MFMA; wave w owns rows 16w..16w+15 ----
            {
                const int grow = c0 + w * 16 + lr;
                bf16x8 afr[4];
                if (grow < seg1) {
                    const float* xp = x + (size_t)grow * DD + lk * 8;
#pragma unroll
                    for (int kk = 0; kk < 4; ++kk) {
                        float4 u0 = *(const float4*)(xp + kk * 32);
                        float4 u1 = *(const float4*)(xp + kk * 32 + 4);
                        us8v uv;
                        uv[0] = f2bf(u0.x); uv[1] = f2bf(u0.y); uv[2] = f2bf(u0.z); uv[3] = f2bf(u0.w);
                        uv[4] = f2bf(u1.x); uv[5] = f2bf(u1.y); uv[6] = f2bf(u1.z); uv[7] = f2bf(u1.w);
                        afr[kk] = __builtin_bit_cast(bf16x8, uv);
                    }
                } else {
                    us8v uz;
#pragma unroll
                    for (int q = 0; q < 8; ++q) uz[q] = 0;
#pragma unroll
                    for (int kk = 0; kk < 4; ++kk) afr[kk] = __builtin_bit_cast(bf16x8, uz);
                }

                f32x4 acc[8];
#pragma unroll
                for (int n = 0; n < 8; ++n) { acc[n][0] = 0.f; acc[n][1] = 0.f; acc[n][2] = 0.f; acc[n][3] = 0.f; }
#pragma unroll
                for (int n = 0; n < 8; ++n) {
#pragma unroll
                    for (int kk = 0; kk < 4; ++kk) {
                        bf16x8 bfr = *(const bf16x8*)&Wt_lds[n * 16 + lr][kk * 32 + lk * 8];
                        acc[n] = __builtin_amdgcn_mfma_f32_16x16x32_bf16(afr[kk], bfr, acc[n], 0, 0, 0);
                    }
                }
                // C layout: col = lane&15, row = (lane>>4)*4 + reg
#pragma unroll
                for (int n = 0; n < 8; ++n) {
                    const int col = n * 16 + lr;
                    const float bb = b_lds[col];
#pragma unroll
                    for (int j = 0; j < 4; ++j) {
                        const int row = w * 16 + lk * 4 + j;
                        h_lds[row][col] = fmaxf(acc[n][j] + bb, 0.f);
                    }
                }
            }
            __syncthreads();

            // ---- phase B: per-node scores s = h.w + b (4 threads/node) ----
            {
                const int node = t >> 2, cg = t & 3;
                const float* hr = &h_lds[node][cg * 32];
                const float* w1p = &w1_lds[cg * 32];
                const float* w2p = &w2_lds[cg * 32];
                float p1 = 0.f, p2 = 0.f;
#pragma unroll
                for (int j = 0; j < 32; ++j) { float hv = hr[j]; p1 += hv * w1p[j]; p2 += hv * w2p[j]; }
                p1 += __shfl_xor(p1, 1); p1 += __shfl_xor(p1, 2);
                p2 += __shfl_xor(p2, 1); p2 += __shfl_xor(p2, 2);
                if (cg == 0) {
                    const bool v = (c0 + node) < seg1;
                    s1_lds[node] = v ? (p1 + bq1) : -INFINITY;
                    s2_lds[node] = v ? (p2 + bq2) : -INFINITY;
                }
            }
            __syncthreads();

            // ---- phase C: online-softmax state update (all waves redundantly, uniform) ----
            {
                const float v1 = s1_lds[l], v2 = s2_lds[l];
                float r1 = v1, r2 = v2;
#pragma unroll
                for (int d = 1; d < 64; d <<= 1) {
                    r1 = fmaxf(r1, __shfl_xor(r1, d));
                    r2 = fmaxf(r2, __shfl_xor(r2, d));
                }
                const float nm1 = fmaxf(m1, r1), nm2 = fmaxf(m2, r2);
                const float sc1 = expf(m1 - nm1), sc2 = expf(m2 - nm2);  // -inf -> 0 on first chunk
                const float e1 = expf(v1 - nm1), e2 = expf(v2 - nm2);    // invalid (-inf) -> 0
                float cz1 = e1, cz2 = e2;
#pragma unroll
                for (int d = 1; d < 64; d <<= 1) { cz1 += __shfl_xor(cz1, d); cz2 += __shfl_xor(cz2, d); }
                z1 = z1 * sc1 + cz1; z2 = z2 * sc2 + cz2;
                m1 = nm1; m2 = nm2;
                if (w == 0) { e1_lds[l] = e1; e2_lds[l] = e2; }
                q1a *= sc1; q2a *= sc2;
            }
            __syncthreads();

            // ---- phase D: accumulate keys/q1/q2 (thread owns (half,col)) ----
            {
                const int i0 = hf * 32;
                const int iend = min(32, seg1 - c0 - i0);
                for (int i = 0; i < iend; ++i) {
                    const int node = i0 + i;
                    const float hv = h_lds[node][c];
                    ka += hv;
                    q1a += e1_lds[node] * hv;
                    q2a += e2_lds[node] * hv;
                }
            }
        }

        // ---- writeout ----
        __syncthreads();
        if (hf == 1) { tmp_lds[0][c] = ka; tmp_lds[1][c] = q1a; tmp_lds[2][c] = q2a; }
        __syncthreads();
        if (hf == 0) {
            const float kt  = ka  + tmp_lds[0][c];
            const float q1t = q1a + tmp_lds[1][c];
            const float q2t = q2a + tmp_lds[2][c];
            out[(size_t)g * DD + c]                   = kt * (1.f / fmaxf((float)cnt, 1.f));
            out[(size_t)(NG + g) * DD + c]            = q1t / fmaxf(z1, 1e-12f);
            out[(size_t)(2 * NG + g) * DD + c]        = q2t / fmaxf(z2, 1e-12f);
        }
    }
}

extern "C" void kernel_launch(void* const* d_in, const int* in_sizes, int n_in,
                              void* d_out, int out_size, void* d_ws, size_t ws_size,
                              hipStream_t stream) {
    const float* x     = (const float*)d_in[0];
    const int*   gid   = (const int*)d_in[1];
    const float* W     = (const float*)d_in[2];
    const float* b_enc = (const float*)d_in[3];
    const float* w_q1  = (const float*)d_in[4];
    const float* b_q1  = (const float*)d_in[5];
    const float* w_q2  = (const float*)d_in[6];
    const float* b_q2  = (const float*)d_in[7];
    float* out = (float*)d_out;

    int* starts        = (int*)d_ws;                                   // (NG+1) ints
    unsigned short* Wt = (unsigned short*)((char*)d_ws + 131072);      // 128*128 bf16

    prep_kernel<<<65, 256, 0, stream>>>(gid, W, starts, Wt);
    fused_kernel<<<2048, 256, 0, stream>>>(x, starts, Wt, b_enc, w_q1, b_q1, w_q2, b_q2, out);
}